// Round 2
// baseline (4712.093 us; speedup 1.0000x reference)
//
#include <hip/hip_runtime.h>
#include <hip/hip_bf16.h>

typedef unsigned short u16;
typedef unsigned int   u32;

#define NB 32
#define CC 64
#define TT 300
#define VV 25
#define OO 128
#define TO 150
#define KT 9

__device__ __forceinline__ float b2f(u16 u){
  union { u32 i; float f; } c; c.i = ((u32)u) << 16; return c.f;
}
__device__ __forceinline__ u16 f2b(float f){
  __hip_bfloat16 h = __float2bfloat16(f);
  return *reinterpret_cast<u16*>(&h);
}
__device__ __forceinline__ float2 bpair(u32 u){
  union { u32 i; float f; } lo, hi;
  lo.i = u << 16; hi.i = u & 0xffff0000u;
  return make_float2(lo.f, hi.f);
}

// ---------------- prep: A_sum (f32) + tcn_w repack Wq[k][i8][o][j] (bf16) ----------------
__global__ __launch_bounds__(256) void k_prep(const float* __restrict__ Ap, const float* __restrict__ ei,
                                              const float* __restrict__ tw, float* __restrict__ Asum,
                                              u16* __restrict__ Wq){
  int idx = blockIdx.x * 256 + threadIdx.x;
  if (idx < VV*VV){
    float s = 0.f;
    for (int p = 0; p < 3; ++p) s += ei[p] * Ap[p*VV*VV + idx];
    Asum[idx] = s;
  }
  int w = idx - 1024;
  if (w >= 0 && w < KT*OO*OO){
    int k  = w / (16*OO*8);
    int r  = w % (16*OO*8);
    int i8 = r / (OO*8);
    int r2 = r % (OO*8);
    int o  = r2 >> 3;
    int j  = r2 & 7;
    // Wq[((k*16+i8)*128+o)*8+j] = tcn_w[o][i8*8+j][k]
    Wq[w] = f2b(tw[o*(OO*KT) + (i8*8 + j)*KT + k]);
  }
}

// ---------------- gcn: per (n,t): agg over v (K=25) then O x C GEMM; out (N,T,V,O) bf16 ----------------
__global__ __launch_bounds__(256) void k_gcn(const float* __restrict__ x, const float* __restrict__ Asum,
                                             const float* __restrict__ gw, const float* __restrict__ gb,
                                             u16* __restrict__ xg){
  __shared__ __align__(16) float aggs[VV][72];   // [w][c], pad 72 to spread banks
  int n = blockIdx.x / TT, t = blockIdx.x % TT;
  int tid = threadIdx.x;
  if (tid < CC){
    int c = tid;
    const float* xr = x + ((size_t)(n*CC + c)*TT + t)*VV;
    float acc[VV];
    #pragma unroll
    for (int w = 0; w < VV; ++w) acc[w] = 0.f;
    for (int v = 0; v < VV; ++v){
      float xv = xr[v];
      #pragma unroll
      for (int w = 0; w < VV; ++w) acc[w] += xv * Asum[v*VV + w];
    }
    #pragma unroll
    for (int w = 0; w < VV; ++w) aggs[w][c] = acc[w];
  }
  __syncthreads();
  int vq = tid & 7, ot = tid >> 3;          // lanes: 8 vq x 8 ot per wave
  int nv = (vq == 0) ? 4 : 3;               // v = vq + 8*j, vq==0 also covers v=24
  float acc[4][4];
  #pragma unroll
  for (int q = 0; q < 4; ++q)
    #pragma unroll
    for (int j = 0; j < 4; ++j) acc[q][j] = 0.f;
  for (int c4 = 0; c4 < CC; c4 += 4){
    float4 a[4];
    for (int j = 0; j < nv; ++j) a[j] = *(const float4*)&aggs[vq + 8*j][c4];
    #pragma unroll
    for (int q = 0; q < 4; ++q){
      int o = ot + q*32;
      float4 g = *(const float4*)&gw[o*CC + c4];
      for (int j = 0; j < nv; ++j)
        acc[q][j] += a[j].x*g.x + a[j].y*g.y + a[j].z*g.z + a[j].w*g.w;
    }
  }
  #pragma unroll
  for (int q = 0; q < 4; ++q){
    int o = ot + q*32;
    float bo = gb[o];
    for (int j = 0; j < nv; ++j){
      int v = vq + 8*j;
      xg[((size_t)(n*TT + t)*VV + v)*OO + o] = f2b(acc[q][j] + bo);
    }
  }
}

// ---------------- tcn: per (n,t2): LDS patch [k][v][i-pairs], each thread 2 o x <=7 v ----------------
__global__ __launch_bounds__(256) void k_tcn(const u16* __restrict__ xg, const u16* __restrict__ Wq,
                                             const float* __restrict__ tb, u16* __restrict__ xt){
  __shared__ __align__(16) u32 xl[KT*VV*64];     // 57.6 KB
  int n = blockIdx.x / TO, t2 = blockIdx.x % TO;
  int tid = threadIdx.x;
  const u32* xgu = (const u32*)xg;
  for (int idx = tid; idx < KT*VV*64; idx += 256){
    int k = idx / (VV*64);
    int r = idx % (VV*64);
    int t = 2*t2 + k - 4;
    u32 val = 0;
    if (t >= 0 && t < TT){
      int v = r / 64, ip = r % 64;
      val = xgu[((size_t)(n*TT + t)*VV + v)*64 + ip];
    }
    xl[idx] = val;
  }
  __syncthreads();
  int ot = tid & 63, vg = tid >> 6;
  int o0 = ot, o1 = ot + 64;
  int v0 = vg*7;
  int nv = VV - v0; if (nv > 7) nv = 7;          // 7,7,7,4 (wave-uniform)
  float acc0[7], acc1[7];
  #pragma unroll
  for (int j = 0; j < 7; ++j){ acc0[j] = 0.f; acc1[j] = 0.f; }
  for (int k = 0; k < KT; ++k){
    const uint4* xk = (const uint4*)&xl[k*VV*64];
    for (int i8 = 0; i8 < 16; ++i8){
      const uint4* wrow = (const uint4*)(Wq + (size_t)((k*16 + i8)*OO)*8);
      uint4 wa = wrow[o0], wb = wrow[o1];        // coalesced 16B/lane
      float2 a0 = bpair(wa.x), a1 = bpair(wa.y), a2 = bpair(wa.z), a3 = bpair(wa.w);
      float2 b0 = bpair(wb.x), b1 = bpair(wb.y), b2 = bpair(wb.z), b3 = bpair(wb.w);
      for (int j = 0; j < nv; ++j){
        uint4 xu = xk[(v0 + j)*16 + i8];         // wave-uniform address -> LDS broadcast
        float2 p0 = bpair(xu.x), p1 = bpair(xu.y), p2 = bpair(xu.z), p3 = bpair(xu.w);
        acc0[j] += p0.x*a0.x + p0.y*a0.y + p1.x*a1.x + p1.y*a1.y
                 + p2.x*a2.x + p2.y*a2.y + p3.x*a3.x + p3.y*a3.y;
        acc1[j] += p0.x*b0.x + p0.y*b0.y + p1.x*b1.x + p1.y*b1.y
                 + p2.x*b2.x + p2.y*b2.y + p3.x*b3.x + p3.y*b3.y;
      }
    }
  }
  float tb0 = tb[o0], tb1 = tb[o1];
  for (int j = 0; j < nv; ++j){
    size_t row = ((size_t)(n*TO + t2)*VV + (v0 + j))*OO;
    xt[row + o0] = f2b(acc0[j] + tb0);
    xt[row + o1] = f2b(acc1[j] + tb1);
  }
}

// ---------------- BN stats, stage 1: per-block partial sums over 480 rows of 128 ----------------
__global__ __launch_bounds__(256) void k_stats1(const u16* __restrict__ xt, float* __restrict__ psum,
                                                float* __restrict__ psq){
  __shared__ float ls[256], lq[256];
  int tid = threadIdx.x;
  int o = tid & 127, rh = tid >> 7;
  int r0 = blockIdx.x * 480;
  float s = 0.f, q = 0.f;
  for (int r = r0 + rh; r < r0 + 480; r += 2){
    float f = b2f(xt[(size_t)r*OO + o]);
    s += f; q += f*f;
  }
  ls[tid] = s; lq[tid] = q;
  __syncthreads();
  if (tid < 128){
    psum[blockIdx.x*128 + o] = ls[tid] + ls[tid + 128];
    psq [blockIdx.x*128 + o] = lq[tid] + lq[tid + 128];
  }
}

// ---------------- BN stats, stage 2: finalize scale/shift per channel ----------------
__global__ __launch_bounds__(128) void k_stats2(const float* __restrict__ psum, const float* __restrict__ psq,
                                                const float* __restrict__ gamma, const float* __restrict__ beta,
                                                float* __restrict__ stats){
  int o = threadIdx.x;
  float s = 0.f, q = 0.f;
  for (int b = 0; b < 250; ++b){ s += psum[b*128 + o]; q += psq[b*128 + o]; }
  const float inv = 1.f / 120000.f;
  float mean = s * inv;
  float var  = q * inv - mean*mean;        // biased, matches jnp.var
  float sc = gamma[o] * rsqrtf(var + 1e-5f);
  stats[o]       = sc;
  stats[128 + o] = beta[o] - mean * sc;
}

// ---------------- final: res GEMM (K=64) + BN affine + relu; out (N,O,T2,V) f32 ----------------
__global__ __launch_bounds__(256) void k_final(const float* __restrict__ x, const u16* __restrict__ xt,
                                               const float* __restrict__ stats, const float* __restrict__ rw,
                                               const float* __restrict__ rb, float* __restrict__ out){
  __shared__ __align__(16) float xs[VV][72];
  int n = blockIdx.x / TO, t2 = blockIdx.x % TO;
  int tid = threadIdx.x;
  const float* xb = x + (size_t)n*CC*TT*VV + (size_t)(2*t2)*VV;  // x[n][c][2*t2][v]
  for (int idx = tid; idx < CC*VV; idx += 256){
    int c = idx / VV, v = idx % VV;
    xs[v][c] = xb[(size_t)c*(TT*VV) + v];
  }
  __syncthreads();
  int vq = tid & 7, ot = tid >> 3;
  int nv = (vq == 0) ? 4 : 3;
  float acc[4][4];
  #pragma unroll
  for (int q = 0; q < 4; ++q)
    #pragma unroll
    for (int j = 0; j < 4; ++j) acc[q][j] = 0.f;
  for (int c4 = 0; c4 < CC; c4 += 4){
    float4 a[4];
    for (int j = 0; j < nv; ++j) a[j] = *(const float4*)&xs[vq + 8*j][c4];
    #pragma unroll
    for (int q = 0; q < 4; ++q){
      int o = ot + q*32;
      float4 g = *(const float4*)&rw[o*CC + c4];
      for (int j = 0; j < nv; ++j)
        acc[q][j] += a[j].x*g.x + a[j].y*g.y + a[j].z*g.z + a[j].w*g.w;
    }
  }
  #pragma unroll
  for (int q = 0; q < 4; ++q){
    int o = ot + q*32;
    float sc = stats[o], sb = stats[128 + o], rbo = rb[o];
    for (int j = 0; j < nv; ++j){
      int v = vq + 8*j;
      float xtv = b2f(xt[((size_t)(n*TO + t2)*VV + v)*OO + o]);
      float r = sc*xtv + sb + acc[q][j] + rbo;
      out[((size_t)(n*OO + o)*TO + t2)*VV + v] = fmaxf(r, 0.f);
    }
  }
}

extern "C" void kernel_launch(void* const* d_in, const int* in_sizes, int n_in,
                              void* d_out, int out_size, void* d_ws, size_t ws_size,
                              hipStream_t stream) {
  const float* x     = (const float*)d_in[0];
  const float* Ap    = (const float*)d_in[1];
  const float* ei    = (const float*)d_in[2];
  const float* gw    = (const float*)d_in[3];
  const float* gb    = (const float*)d_in[4];
  const float* tw    = (const float*)d_in[5];
  const float* tb    = (const float*)d_in[6];
  const float* gamma = (const float*)d_in[7];
  const float* beta  = (const float*)d_in[8];
  const float* rw    = (const float*)d_in[9];
  const float* rb    = (const float*)d_in[10];
  float* out = (float*)d_out;

  char* ws = (char*)d_ws;
  float* Asum  = (float*)ws;                      // 2500 B
  u16*   Wq    = (u16*)(ws + 4096);               // 294912 B -> 299008
  float* psum  = (float*)(ws + 299008);           // 128000 B -> 427008
  float* psq   = (float*)(ws + 427008);           // 128000 B -> 555008
  float* stats = (float*)(ws + 555008);           // 1024 B
  u16*   xg    = (u16*)(ws + (1u<<20));           // 61,440,000 B  (N,T,V,O) bf16
  u16*   xt    = (u16*)(ws + 62488576);           // 28,800,000 B  (N,T2,V,O) bf16; total ~91.3 MB

  k_prep  <<<dim3(580),    dim3(256), 0, stream>>>(Ap, ei, tw, Asum, Wq);
  k_gcn   <<<dim3(NB*TT),  dim3(256), 0, stream>>>(x, Asum, gw, gb, xg);
  k_tcn   <<<dim3(NB*TO),  dim3(256), 0, stream>>>(xg, Wq, tb, xt);
  k_stats1<<<dim3(250),    dim3(256), 0, stream>>>(xt, psum, psq);
  k_stats2<<<dim3(1),      dim3(128), 0, stream>>>(psum, psq, gamma, beta, stats);
  k_final <<<dim3(NB*TO),  dim3(256), 0, stream>>>(x, xt, stats, rw, rb, out);
}

// Round 3
// 2545.299 us; speedup vs baseline: 1.8513x; 1.8513x over previous
//
#include <hip/hip_runtime.h>
#include <hip/hip_bf16.h>

typedef unsigned short u16;
typedef unsigned int   u32;

#define NB 32
#define CC 64
#define TT 300
#define VV 25
#define OO 128
#define TO 150
#define KT 9

typedef short s8v  __attribute__((ext_vector_type(8)));
typedef float f4v  __attribute__((ext_vector_type(4)));

__device__ __forceinline__ float b2f(u16 u){
  union { u32 i; float f; } c; c.i = ((u32)u) << 16; return c.f;
}
__device__ __forceinline__ u16 f2b(float f){
  __hip_bfloat16 h = __float2bfloat16(f);
  return *reinterpret_cast<u16*>(&h);
}
__device__ __forceinline__ void async16(const void* g, void* l){
  __builtin_amdgcn_global_load_lds((const __attribute__((address_space(1))) u32*)g,
                                   (__attribute__((address_space(3))) u32*)l, 16, 0, 0);
}

// ---------------- prep: A_sum (f32) + zero-page + tcn_w repack Wq2[kc][o][64] (bf16) ----------------
__global__ __launch_bounds__(256) void k_prep(const float* __restrict__ Ap, const float* __restrict__ ei,
                                              const float* __restrict__ tw, float* __restrict__ Asum,
                                              float* __restrict__ zbuf, u16* __restrict__ Wq2){
  int idx = blockIdx.x * 256 + threadIdx.x;
  if (idx < VV*VV){
    float s = 0.f;
    for (int p = 0; p < 3; ++p) s += ei[p] * Ap[p*VV*VV + idx];
    Asum[idx] = s;
  }
  if (idx >= 640 && idx < 768) zbuf[idx - 640] = 0.f;   // 512 B zero page for conv halo
  int w = idx - 1024;
  if (w >= 0 && w < 18*OO*64){
    int kc = w >> 13;            // /8192
    int r  = w & 8191;
    int o  = r >> 6;
    int j  = r & 63;
    int k  = kc >> 1;
    int i  = (kc & 1)*64 + j;
    // Wq2[kc][o][j] = tcn_w[o][i][k]
    Wq2[w] = f2b(tw[o*(OO*KT) + i*KT + k]);
  }
}

// ---------------- gcn: per (n,t): agg over v (K=25) then O x C GEMM; out (N,T,V,O) bf16 ----------------
__global__ __launch_bounds__(256) void k_gcn(const float* __restrict__ x, const float* __restrict__ Asum,
                                             const float* __restrict__ gw, const float* __restrict__ gb,
                                             u16* __restrict__ xg){
  __shared__ __align__(16) float aggs[VV][72];
  int n = blockIdx.x / TT, t = blockIdx.x % TT;
  int tid = threadIdx.x;
  if (tid < CC){
    int c = tid;
    const float* xr = x + ((size_t)(n*CC + c)*TT + t)*VV;
    float acc[VV];
    #pragma unroll
    for (int w = 0; w < VV; ++w) acc[w] = 0.f;
    for (int v = 0; v < VV; ++v){
      float xv = xr[v];
      #pragma unroll
      for (int w = 0; w < VV; ++w) acc[w] += xv * Asum[v*VV + w];
    }
    #pragma unroll
    for (int w = 0; w < VV; ++w) aggs[w][c] = acc[w];
  }
  __syncthreads();
  int vq = tid & 7, ot = tid >> 3;
  int nv = (vq == 0) ? 4 : 3;
  float acc[4][4];
  #pragma unroll
  for (int q = 0; q < 4; ++q)
    #pragma unroll
    for (int j = 0; j < 4; ++j) acc[q][j] = 0.f;
  for (int c4 = 0; c4 < CC; c4 += 4){
    float4 a[4];
    for (int j = 0; j < nv; ++j) a[j] = *(const float4*)&aggs[vq + 8*j][c4];
    #pragma unroll
    for (int q = 0; q < 4; ++q){
      int o = ot + q*32;
      float4 g = *(const float4*)&gw[o*CC + c4];
      for (int j = 0; j < nv; ++j)
        acc[q][j] += a[j].x*g.x + a[j].y*g.y + a[j].z*g.z + a[j].w*g.w;
    }
  }
  #pragma unroll
  for (int q = 0; q < 4; ++q){
    int o = ot + q*32;
    float bo = gb[o];
    for (int j = 0; j < nv; ++j){
      int v = vq + 8*j;
      xg[((size_t)(n*TT + t)*VV + v)*OO + o] = f2b(acc[q][j] + bo);
    }
  }
}

// ---------------- tcn as MFMA implicit GEMM: M=(v*150+t2) per n, N=128 o, K=1152 ----------------
// xt layout: [n][m=v*150+t2][o]
__global__ __launch_bounds__(256) void k_tcnm(const u16* __restrict__ xg, const u16* __restrict__ Wq2,
                                              const float* __restrict__ tb, const u16* __restrict__ zbuf,
                                              u16* __restrict__ xt){
  __shared__ __align__(16) u16 A_lds[128*64];   // 16 KB, rows m, 64 k-elems, XOR-swizzled granules
  __shared__ __align__(16) u16 B_lds[128*64];   // 16 KB, rows o, 64 k-elems, XOR-swizzled granules
  int bx = blockIdx.x;
  int n  = bx / 30;
  int m0 = (bx % 30) * 128;
  int tid = threadIdx.x;
  int lane = tid & 63, wv = tid >> 6;
  int wm = (wv & 1) * 64, wo = (wv >> 1) * 64;
  int lr = lane & 15, lq = lane >> 4;

  // staging precompute: thread handles rows r = it*32 + (tid>>3), granule p = tid&7
  int rlow = tid >> 3;
  int gsrc = (tid & 7) ^ (rlow & 7);            // source granule (XOR swizzle on source)
  int tid16 = tid * 16;                          // LDS dest byte offset (lane-contiguous)
  int  mrow[4], tbase[4]; size_t c0[4]; bool vm[4];
  #pragma unroll
  for (int it = 0; it < 4; ++it){
    int m = m0 + it*32 + rlow;
    mrow[it] = m;
    vm[it] = (m < 3750);
    int v  = m / TO, t2 = m % TO;
    tbase[it] = 2*t2 - 4;
    c0[it] = (size_t)n*(TT*VV*OO) + (size_t)v*OO + gsrc*8;
  }

  f4v acc[4][4];
  #pragma unroll
  for (int mi = 0; mi < 4; ++mi)
    #pragma unroll
    for (int ni = 0; ni < 4; ++ni) acc[mi][ni] = (f4v)(0.f);

  for (int kc = 0; kc < 18; ++kc){
    int k  = kc >> 1;
    int i0 = (kc & 1) * 64;
    const u16* wbase = Wq2 + kc*8192;
    #pragma unroll
    for (int it = 0; it < 4; ++it){
      int t = tbase[it] + k;
      const u16* ga = (vm[it] && t >= 0 && t < TT)
                      ? xg + c0[it] + (size_t)t*(VV*OO) + i0
                      : zbuf;
      async16(ga, (char*)A_lds + it*4096 + tid16);
      async16(wbase + ((it*32 + rlow)*64 + gsrc*8), (char*)B_lds + it*4096 + tid16);
    }
    __syncthreads();
    #pragma unroll
    for (int ks = 0; ks < 2; ++ks){
      int p = ((ks*4 + lq) ^ (lane & 7)) * 8;    // physical element offset of logical granule
      s8v af[4], bf[4];
      #pragma unroll
      for (int mi = 0; mi < 4; ++mi)
        af[mi] = *(const s8v*)&A_lds[(wm + mi*16 + lr)*64 + p];
      #pragma unroll
      for (int ni = 0; ni < 4; ++ni)
        bf[ni] = *(const s8v*)&B_lds[(wo + ni*16 + lr)*64 + p];
      #pragma unroll
      for (int mi = 0; mi < 4; ++mi)
        #pragma unroll
        for (int ni = 0; ni < 4; ++ni)
          acc[mi][ni] = __builtin_amdgcn_mfma_f32_16x16x32_bf16(af[mi], bf[ni], acc[mi][ni], 0, 0, 0);
    }
    __syncthreads();
  }

  // epilogue: D[m][o], m = m0+wm+mi*16+lq*4+rg, o = wo+ni*16+lr
  float bias[4];
  #pragma unroll
  for (int ni = 0; ni < 4; ++ni) bias[ni] = tb[wo + ni*16 + lr];
  #pragma unroll
  for (int mi = 0; mi < 4; ++mi){
    int mr = m0 + wm + mi*16 + lq*4;
    #pragma unroll
    for (int ni = 0; ni < 4; ++ni){
      int o = wo + ni*16 + lr;
      #pragma unroll
      for (int rg = 0; rg < 4; ++rg){
        int m = mr + rg;
        if (m < 3750)
          xt[((size_t)n*3750 + m)*OO + o] = f2b(acc[mi][ni][rg] + bias[ni]);
      }
    }
  }
}

// ---------------- BN stats, stage 1: per-block partial sums over 480 rows of 128 ----------------
__global__ __launch_bounds__(256) void k_stats1(const u16* __restrict__ xt, float* __restrict__ psum,
                                                float* __restrict__ psq){
  __shared__ float ls[256], lq[256];
  int tid = threadIdx.x;
  int o = tid & 127, rh = tid >> 7;
  int r0 = blockIdx.x * 480;
  float s = 0.f, q = 0.f;
  for (int r = r0 + rh; r < r0 + 480; r += 2){
    float f = b2f(xt[(size_t)r*OO + o]);
    s += f; q += f*f;
  }
  ls[tid] = s; lq[tid] = q;
  __syncthreads();
  if (tid < 128){
    psum[blockIdx.x*128 + o] = ls[tid] + ls[tid + 128];
    psq [blockIdx.x*128 + o] = lq[tid] + lq[tid + 128];
  }
}

// ---------------- BN stats, stage 2: finalize scale/shift per channel ----------------
__global__ __launch_bounds__(128) void k_stats2(const float* __restrict__ psum, const float* __restrict__ psq,
                                                const float* __restrict__ gamma, const float* __restrict__ beta,
                                                float* __restrict__ stats){
  int o = threadIdx.x;
  float s = 0.f, q = 0.f;
  for (int b = 0; b < 250; ++b){ s += psum[b*128 + o]; q += psq[b*128 + o]; }
  const float inv = 1.f / 120000.f;
  float mean = s * inv;
  float var  = q * inv - mean*mean;        // biased, matches jnp.var
  float sc = gamma[o] * rsqrtf(var + 1e-5f);
  stats[o]       = sc;
  stats[128 + o] = beta[o] - mean * sc;
}

// ---------------- final: res GEMM (K=64) + BN affine + relu; out (N,O,T2,V) f32 ----------------
__global__ __launch_bounds__(256) void k_final(const float* __restrict__ x, const u16* __restrict__ xt,
                                               const float* __restrict__ stats, const float* __restrict__ rw,
                                               const float* __restrict__ rb, float* __restrict__ out){
  __shared__ __align__(16) float xs[VV][72];
  int n = blockIdx.x / TO, t2 = blockIdx.x % TO;
  int tid = threadIdx.x;
  const float* xb = x + (size_t)n*CC*TT*VV + (size_t)(2*t2)*VV;  // x[n][c][2*t2][v]
  for (int idx = tid; idx < CC*VV; idx += 256){
    int c = idx / VV, v = idx % VV;
    xs[v][c] = xb[(size_t)c*(TT*VV) + v];
  }
  __syncthreads();
  int vq = tid & 7, ot = tid >> 3;
  int nv = (vq == 0) ? 4 : 3;
  float acc[4][4];
  #pragma unroll
  for (int q = 0; q < 4; ++q)
    #pragma unroll
    for (int j = 0; j < 4; ++j) acc[q][j] = 0.f;
  for (int c4 = 0; c4 < CC; c4 += 4){
    float4 a[4];
    for (int j = 0; j < nv; ++j) a[j] = *(const float4*)&xs[vq + 8*j][c4];
    #pragma unroll
    for (int q = 0; q < 4; ++q){
      int o = ot + q*32;
      float4 g = *(const float4*)&rw[o*CC + c4];
      for (int j = 0; j < nv; ++j)
        acc[q][j] += a[j].x*g.x + a[j].y*g.y + a[j].z*g.z + a[j].w*g.w;
    }
  }
  #pragma unroll
  for (int q = 0; q < 4; ++q){
    int o = ot + q*32;
    float sc = stats[o], sb = stats[128 + o], rbo = rb[o];
    for (int j = 0; j < nv; ++j){
      int v = vq + 8*j;
      // xt layout: [n][m=v*150+t2][o]
      float xtv = b2f(xt[((size_t)n*3750 + (size_t)v*TO + t2)*OO + o]);
      float r = sc*xtv + sb + acc[q][j] + rbo;
      out[((size_t)(n*OO + o)*TO + t2)*VV + v] = fmaxf(r, 0.f);
    }
  }
}

extern "C" void kernel_launch(void* const* d_in, const int* in_sizes, int n_in,
                              void* d_out, int out_size, void* d_ws, size_t ws_size,
                              hipStream_t stream) {
  const float* x     = (const float*)d_in[0];
  const float* Ap    = (const float*)d_in[1];
  const float* ei    = (const float*)d_in[2];
  const float* gw    = (const float*)d_in[3];
  const float* gb    = (const float*)d_in[4];
  const float* tw    = (const float*)d_in[5];
  const float* tb    = (const float*)d_in[6];
  const float* gamma = (const float*)d_in[7];
  const float* beta  = (const float*)d_in[8];
  const float* rw    = (const float*)d_in[9];
  const float* rb    = (const float*)d_in[10];
  float* out = (float*)d_out;

  char* ws = (char*)d_ws;
  float* Asum  = (float*)ws;                      // 2500 B
  float* zbuf  = (float*)(ws + 2560);             // 512 B zero page
  u16*   Wq2   = (u16*)(ws + 4096);               // 294912 B -> 299008
  float* psum  = (float*)(ws + 299008);           // 128000 B -> 427008
  float* psq   = (float*)(ws + 427008);           // 128000 B -> 555008
  float* stats = (float*)(ws + 555008);           // 1024 B
  u16*   xg    = (u16*)(ws + (1u<<20));           // 61,440,000 B  (N,T,V,O) bf16
  u16*   xt    = (u16*)(ws + 62488576);           // 28,800,000 B  [n][m][o] bf16; total ~91.3 MB

  k_prep  <<<dim3(580),    dim3(256), 0, stream>>>(Ap, ei, tw, Asum, zbuf, Wq2);
  k_gcn   <<<dim3(NB*TT),  dim3(256), 0, stream>>>(x, Asum, gw, gb, xg);
  k_tcnm  <<<dim3(NB*30),  dim3(256), 0, stream>>>(xg, Wq2, tb, (const u16*)zbuf, xt);
  k_stats1<<<dim3(250),    dim3(256), 0, stream>>>(xt, psum, psq);
  k_stats2<<<dim3(1),      dim3(128), 0, stream>>>(psum, psq, gamma, beta, stats);
  k_final <<<dim3(NB*TO),  dim3(256), 0, stream>>>(x, xt, stats, rw, rb, out);
}